// Round 3
// baseline (547.761 us; speedup 1.0000x reference)
//
#include <hip/hip_runtime.h>
#include <hip/hip_cooperative_groups.h>
#include <math.h>

#define LEVEL 16
#define COOP_BLOCKS 1024
#define THREADS 256

// fallback-path config (proven round-2 kernels)
#define RED_BLOCKS 2048
#define RED_THREADS 256

typedef float f32x4 __attribute__((ext_vector_type(4)));

namespace cg = cooperative_groups;

// ================= Fused cooperative kernel =================
// Phase A: per-column sum over t, |.|, block partials (each block owns a
//          strided set of columns).
// grid.sync()
// vth:     every block reduces the COOP_BLOCKS partials in the SAME fixed
//          order -> bit-identical vth everywhere, no extra sync needed.
// Phase B: each block scans exactly the columns it reduced in phase A --
//          those lines were just read by this block, so the re-read hits
//          its own XCD L2 / the L3 with minimal time gap.
__global__ __launch_bounds__(THREADS, 4) void bif_fused(
    const f32x4* __restrict__ x, f32x4* __restrict__ out,
    double* __restrict__ partial, int M4, int Mtotal)
{
    cg::grid_group grid = cg::this_grid();

    const int tid = blockIdx.x * blockDim.x + threadIdx.x;
    const int nthreads = gridDim.x * blockDim.x;

    // ---------- Phase A ----------
    double acc = 0.0;
    for (int m = tid; m < M4; m += nthreads) {
        float sx = 0.f, sy = 0.f, sz = 0.f, sw = 0.f;
        #pragma unroll
        for (int t = 0; t < LEVEL; ++t) {
            f32x4 v = x[(size_t)t * M4 + m];
            sx += v.x; sy += v.y; sz += v.z; sw += v.w;
        }
        acc += (double)fabsf(sx) + (double)fabsf(sy)
             + (double)fabsf(sz) + (double)fabsf(sw);
    }
    for (int off = 32; off > 0; off >>= 1)
        acc += __shfl_down(acc, off, 64);

    __shared__ double wsum[THREADS / 64];
    if ((threadIdx.x & 63) == 0) wsum[threadIdx.x >> 6] = acc;
    __syncthreads();
    if (threadIdx.x == 0) {
        double b = 0.0;
        #pragma unroll
        for (int w = 0; w < THREADS / 64; ++w) b += wsum[w];
        partial[blockIdx.x] = b;
    }

    grid.sync();

    // ---------- vth (identical fixed-order reduction in every block) ----------
    __shared__ double sred[THREADS];
    {
        const int per = COOP_BLOCKS / THREADS;   // 4
        double s = 0.0;
        #pragma unroll
        for (int k = 0; k < per; ++k)
            s += partial[threadIdx.x * per + k];
        sred[threadIdx.x] = s;
    }
    __syncthreads();
    for (int s = THREADS / 2; s > 0; s >>= 1) {
        if (threadIdx.x < s) sred[threadIdx.x] += sred[threadIdx.x + s];
        __syncthreads();
    }
    __shared__ float s_vth;
    if (threadIdx.x == 0) {
        float mean = (float)(sred[0] / (double)Mtotal);
        s_vth = mean * 2.0f / sqrtf(15.0f);
    }
    __syncthreads();
    const float vth = s_vth;

    // ---------- Phase B ----------
    for (int m = tid; m < M4; m += nthreads) {
        f32x4 xv[LEVEL];
        #pragma unroll
        for (int t = 0; t < LEVEL; ++t)
            xv[t] = __builtin_nontemporal_load(&x[(size_t)t * M4 + m]);

        float v[4], T[4];
        #pragma unroll
        for (int c = 0; c < 4; ++c) { v[c] = 0.5f * vth; T[c] = 0.f; }

        #pragma unroll
        for (int t = 0; t < LEVEL; ++t) {
            float in[4] = { xv[t].x, xv[t].y, xv[t].z, xv[t].w };
            f32x4 ov;
            #pragma unroll
            for (int c = 0; c < 4; ++c) {
                float vv = v[c] + in[c];
                bool pos = ((vv - vth) >= 0.f) && ((T[c] - 15.f) < 0.f);
                bool neg = (vv < 0.f) && (T[c] > 0.f);
                float spike = neg ? -1.f : (pos ? 1.f : 0.f);
                vv -= vth * spike;
                T[c] += spike;
                v[c] = vv;
                ov[c] = spike * vth;
            }
            __builtin_nontemporal_store(ov, &out[(size_t)t * M4 + m]);
        }
    }
}

// ================= Fallback path (round-2 proven kernels) =================
__global__ __launch_bounds__(RED_THREADS) void colsum_abs_partial(
    const f32x4* __restrict__ x, double* __restrict__ partial, int M4)
{
    int tid = blockIdx.x * blockDim.x + threadIdx.x;
    int nthreads = gridDim.x * blockDim.x;

    double acc = 0.0;
    for (int m = tid; m < M4; m += nthreads) {
        float sx = 0.f, sy = 0.f, sz = 0.f, sw = 0.f;
        #pragma unroll
        for (int t = 0; t < LEVEL; ++t) {
            f32x4 v = x[(size_t)t * M4 + m];
            sx += v.x; sy += v.y; sz += v.z; sw += v.w;
        }
        acc += (double)fabsf(sx) + (double)fabsf(sy)
             + (double)fabsf(sz) + (double)fabsf(sw);
    }
    for (int off = 32; off > 0; off >>= 1)
        acc += __shfl_down(acc, off, 64);

    __shared__ double wsum[RED_THREADS / 64];
    int lane = threadIdx.x & 63;
    int wid  = threadIdx.x >> 6;
    if (lane == 0) wsum[wid] = acc;
    __syncthreads();
    if (threadIdx.x == 0) {
        double b = 0.0;
        #pragma unroll
        for (int w = 0; w < RED_THREADS / 64; ++w) b += wsum[w];
        partial[blockIdx.x] = b;
    }
}

__global__ __launch_bounds__(256) void finalize_vth(
    const double* __restrict__ partial, float* __restrict__ vth_out, int nb, int Mtotal)
{
    __shared__ double sdata[256];
    double a = 0.0;
    for (int i = threadIdx.x; i < nb; i += blockDim.x) a += partial[i];
    sdata[threadIdx.x] = a;
    __syncthreads();
    for (int s = 128; s > 0; s >>= 1) {
        if (threadIdx.x < s) sdata[threadIdx.x] += sdata[threadIdx.x + s];
        __syncthreads();
    }
    if (threadIdx.x == 0) {
        float mean = (float)(sdata[0] / (double)Mtotal);
        vth_out[0] = mean * 2.0f / sqrtf(15.0f);
    }
}

__global__ __launch_bounds__(256) void bif_scan(
    const f32x4* __restrict__ x, f32x4* __restrict__ out,
    const float* __restrict__ vth_p, int M4)
{
    int bid = gridDim.x - 1 - blockIdx.x;
    int m = bid * blockDim.x + threadIdx.x;
    if (m >= M4) return;

    const float vth = vth_p[0];

    f32x4 xv[LEVEL];
    #pragma unroll
    for (int t = 0; t < LEVEL; ++t)
        xv[t] = __builtin_nontemporal_load(&x[(size_t)t * M4 + m]);

    float v[4], T[4];
    #pragma unroll
    for (int c = 0; c < 4; ++c) { v[c] = 0.5f * vth; T[c] = 0.f; }

    #pragma unroll
    for (int t = 0; t < LEVEL; ++t) {
        float in[4] = { xv[t].x, xv[t].y, xv[t].z, xv[t].w };
        f32x4 ov;
        #pragma unroll
        for (int c = 0; c < 4; ++c) {
            float vv = v[c] + in[c];
            bool pos = ((vv - vth) >= 0.f) && ((T[c] - 15.f) < 0.f);
            bool neg = (vv < 0.f) && (T[c] > 0.f);
            float spike = neg ? -1.f : (pos ? 1.f : 0.f);
            vv -= vth * spike;
            T[c] += spike;
            v[c] = vv;
            ov[c] = spike * vth;
        }
        __builtin_nontemporal_store(ov, &out[(size_t)t * M4 + m]);
    }
}

extern "C" void kernel_launch(void* const* d_in, const int* in_sizes, int n_in,
                              void* d_out, int out_size, void* d_ws, size_t ws_size,
                              hipStream_t stream)
{
    const float* x = (const float*)d_in[0];
    float* out = (float*)d_out;
    const int total = in_sizes[0];          // 67,108,864
    int M = total / LEVEL;                  // 4,194,304 columns
    int M4 = M / 4;                         // 1,048,576 float4 columns

    double* partials = (double*)d_ws;       // up to RED_BLOCKS doubles
    float* vth = (float*)((char*)d_ws + RED_BLOCKS * sizeof(double));

    const f32x4* xv = (const f32x4*)x;
    f32x4* outv = (f32x4*)out;

    void* args[] = { (void*)&xv, (void*)&outv, (void*)&partials,
                     (void*)&M4, (void*)&M };
    hipError_t e = hipLaunchCooperativeKernel(
        (const void*)bif_fused, dim3(COOP_BLOCKS), dim3(THREADS),
        args, 0, stream);

    if (e != hipSuccess) {
        // clear sticky error, run the proven 3-kernel path
        (void)hipGetLastError();
        colsum_abs_partial<<<RED_BLOCKS, RED_THREADS, 0, stream>>>(
            (const f32x4*)x, partials, M4);
        finalize_vth<<<1, 256, 0, stream>>>(partials, vth, RED_BLOCKS, M);
        int blocks = (M4 + 255) / 256;
        bif_scan<<<blocks, 256, 0, stream>>>(
            (const f32x4*)x, (f32x4*)outv, vth, M4);
    }
}